// Round 1
// baseline (1653.342 us; speedup 1.0000x reference)
//
#include <hip/hip_runtime.h>
#include <math.h>

#define NB   200
#define DIMH 128
#define ROWS 4
#define TPB  256

__device__ __forceinline__ float pow10_(float x){
    float x2 = x*x; float x4 = x2*x2; float x8 = x4*x4; return x8*x2;
}
__device__ __forceinline__ float wsum(float v){
    #pragma unroll
    for (int m = 1; m < 64; m <<= 1) v += __shfl_xor(v, m, 64);
    return v;
}
__device__ __forceinline__ float wmax(float v){
    #pragma unroll
    for (int m = 1; m < 64; m <<= 1) v = fmaxf(v, __shfl_xor(v, m, 64));
    return v;
}

__global__ __launch_bounds__(TPB) void la_fused(
    const float* __restrict__ hidden,
    const int*   __restrict__ adj,
    const int*   __restrict__ mask,
    const float* __restrict__ a0, const float* __restrict__ a1,
    const float* __restrict__ a2, const float* __restrict__ a3,
    const float* __restrict__ W,  const float* __restrict__ bias,
    float* __restrict__ out)
{
    __shared__ float ha[ROWS][4][132];   // h_i[d]*a_k[d], padded stride vs bank conflicts
    __shared__ float hi[ROWS][DIMH];
    __shared__ float xs[ROWS][256];      // Xs values, then reused to hold normalized p
    __shared__ float ov[ROWS][DIMH];

    const int t   = threadIdx.x;
    const int bid = blockIdx.x;
    const int b   = bid / (NB / ROWS);
    const int i0  = (bid % (NB / ROWS)) * ROWS;

    const float* hb = hidden + (size_t)b * NB * DIMH;

    // ---- stage h_i rows and ha table ----
    for (int idx = t; idx < ROWS * DIMH; idx += TPB) {
        int r = idx >> 7, d = idx & 127;
        hi[r][d] = hb[(i0 + r) * DIMH + d];
    }
    for (int idx = t; idx < ROWS * 4 * DIMH; idx += TPB) {
        int r = idx >> 9, k = (idx >> 7) & 3, d = idx & 127;
        float av = (k == 0) ? a0[d] : (k == 1) ? a1[d] : (k == 2) ? a2[d] : a3[d];
        ha[r][k][d] = hb[(i0 + r) * DIMH + d] * av;
    }
    __syncthreads();

    // ---- phase S: thread t owns column j=t for all 4 rows ----
    if (t < NB) {
        const int m = mask[b * NB + t];
        int kk[ROWS];
        #pragma unroll
        for (int r = 0; r < ROWS; r++)
            kk[r] = adj[((size_t)(b * NB + i0 + r)) * NB + t];
        int ksel[ROWS];
        #pragma unroll
        for (int r = 0; r < ROWS; r++) ksel[r] = (kk[r] > 0) ? (kk[r] - 1) : 0;

        float acc[ROWS] = {0.f, 0.f, 0.f, 0.f};
        const float* hj = hb + t * DIMH;
        for (int d = 0; d < DIMH; d += 4) {
            float4 hv = *(const float4*)(hj + d);
            #pragma unroll
            for (int r = 0; r < ROWS; r++) {
                const float4 av4 = *(const float4*)&ha[r][ksel[r]][d];
                acc[r] = fmaf(hv.x, av4.x, acc[r]);
                acc[r] = fmaf(hv.y, av4.y, acc[r]);
                acc[r] = fmaf(hv.z, av4.z, acc[r]);
                acc[r] = fmaf(hv.w, av4.w, acc[r]);
            }
        }
        #pragma unroll
        for (int r = 0; r < ROWS; r++) {
            float x;
            if (m == 0)           x = -INFINITY;           // mask fill
            else if (kk[r] == 0)  x = 0.0f;                // no edge: sel=0 -> Xs=0
            else {
                float e = acc[r];
                e = (e >= 0.0f) ? e : 0.2f * e;            // leaky relu 0.2
                x = e * 0.1f;                              // * (alpha-1)
            }
            xs[r][t] = x;
        }
    } else {
        #pragma unroll
        for (int r = 0; r < ROWS; r++) xs[r][t] = -INFINITY;  // pad
    }
    __syncthreads();

    // ---- entmax bisection: wave w owns row r=w (wave-local, shuffle reduces) ----
    const int lane = t & 63;
    const int r    = t >> 6;
    float x0 = xs[r][lane];
    float x1 = xs[r][lane + 64];
    float x2 = xs[r][lane + 128];
    float x3 = xs[r][lane + 192];

    float mx  = wmax(fmaxf(fmaxf(x0, x1), fmaxf(x2, x3)));
    float tau = mx - 1.0f;
    float s0  = pow10_(fmaxf(x0 - tau, 0.f)) + pow10_(fmaxf(x1 - tau, 0.f))
              + pow10_(fmaxf(x2 - tau, 0.f)) + pow10_(fmaxf(x3 - tau, 0.f));
    float f_lo = wsum(s0) - 1.0f;                  // captured once, never updated (matches ref)
    float dm   = (mx - 0.58870401f) - tau;         // tau_hi - tau_lo; (1/200)^0.1

    for (int itn = 0; itn < 50; ++itn) {
        dm *= 0.5f;
        float tm = tau + dm;
        float s = pow10_(fmaxf(x0 - tm, 0.f)) + pow10_(fmaxf(x1 - tm, 0.f))
                + pow10_(fmaxf(x2 - tm, 0.f)) + pow10_(fmaxf(x3 - tm, 0.f));
        float fm = wsum(s) - 1.0f;
        if (fm * f_lo >= 0.0f) tau = tm;
    }
    float p0 = pow10_(fmaxf(x0 - tau, 0.f));
    float p1 = pow10_(fmaxf(x1 - tau, 0.f));
    float p2 = pow10_(fmaxf(x2 - tau, 0.f));
    float p3 = pow10_(fmaxf(x3 - tau, 0.f));
    float sinv = 1.0f / wsum(p0 + p1 + p2 + p3);   // ensure_sum_one
    xs[r][lane]       = p0 * sinv;
    xs[r][lane + 64]  = p1 * sinv;
    xs[r][lane + 128] = p2 * sinv;
    xs[r][lane + 192] = p3 * sinv;
    // wave-local LDS write->read below: no block barrier needed (row owned by this wave)

    // ---- PV: out_row[d] = sum_j p[j] * h[b,j,d]; lanes cover d, d+64 ----
    const int d0 = lane, d1 = lane + 64;
    float o0 = 0.f, o1 = 0.f;
    for (int j = 0; j < NB; ++j) {
        float pj = xs[r][j];                       // broadcast read
        o0 = fmaf(pj, hb[j * DIMH + d0], o0);
        o1 = fmaf(pj, hb[j * DIMH + d1], o1);
    }
    ov[r][d0] = o0;
    ov[r][d1] = o1;

    // ---- gate: sigmoid([h_i, o] @ W + b), then mix ----
    float g0 = bias[d0], g1 = bias[d1];
    for (int e = 0; e < DIMH; ++e) {
        float c = hi[r][e];
        g0 = fmaf(c, W[e * DIMH + d0], g0);
        g1 = fmaf(c, W[e * DIMH + d1], g1);
    }
    for (int e = 0; e < DIMH; ++e) {
        float c = ov[r][e];
        g0 = fmaf(c, W[(DIMH + e) * DIMH + d0], g0);
        g1 = fmaf(c, W[(DIMH + e) * DIMH + d1], g1);
    }
    float sg0 = 1.0f / (1.0f + __expf(-g0));
    float sg1 = 1.0f / (1.0f + __expf(-g1));

    const size_t gi = (size_t)(b * NB + i0 + r) * DIMH;
    out[gi + d0] = sg0 * o0 + (1.0f - sg0) * hi[r][d0];
    out[gi + d1] = sg1 * o1 + (1.0f - sg1) * hi[r][d1];
}

extern "C" void kernel_launch(void* const* d_in, const int* in_sizes, int n_in,
                              void* d_out, int out_size, void* d_ws, size_t ws_size,
                              hipStream_t stream)
{
    const float* hidden = (const float*)d_in[0];
    const int*   adj    = (const int*)d_in[1];
    const int*   mask   = (const int*)d_in[2];
    const float* a0     = (const float*)d_in[3];
    const float* a1     = (const float*)d_in[4];
    const float* a2     = (const float*)d_in[5];
    const float* a3     = (const float*)d_in[6];
    const float* W      = (const float*)d_in[7];
    const float* bias   = (const float*)d_in[8];
    float* out = (float*)d_out;

    const int B = in_sizes[0] / (NB * DIMH);   // 256
    dim3 grid(B * (NB / ROWS));
    la_fused<<<grid, TPB, 0, stream>>>(hidden, adj, mask, a0, a1, a2, a3, W, bias, out);
}

// Round 2
// 827.858 us; speedup vs baseline: 1.9971x; 1.9971x over previous
//
#include <hip/hip_runtime.h>
#include <math.h>

#define NB    200
#define DIMH  128
#define ROWS  4
#define TPB   256
#define NITER 34   // 50 in ref; iterations >~28 are f32 no-ops (dm < half-ulp(tau)), bit-identical

__device__ __forceinline__ float pow10_(float x){
    float x2 = x*x; float x4 = x2*x2; float x8 = x4*x4; return x8*x2;
}
__device__ __forceinline__ float wsum(float v){
    #pragma unroll
    for (int m = 1; m < 64; m <<= 1) v += __shfl_xor(v, m, 64);
    return v;
}
__device__ __forceinline__ float wmax(float v){
    #pragma unroll
    for (int m = 1; m < 64; m <<= 1) v = fmaxf(v, __shfl_xor(v, m, 64));
    return v;
}

__global__ __launch_bounds__(TPB, 4) void la_fused(
    const float* __restrict__ hidden,
    const int*   __restrict__ adj,
    const int*   __restrict__ mask,
    const float* __restrict__ a0, const float* __restrict__ a1,
    const float* __restrict__ a2, const float* __restrict__ a3,
    const float* __restrict__ W,  const float* __restrict__ bias,
    float* __restrict__ out)
{
    __shared__ float ha[ROWS][4][132];   // h_i[d]*a_k[d], padded stride
    __shared__ float hi[ROWS][DIMH];
    __shared__ float xs[ROWS][256];      // Xs, later normalized p
    __shared__ float ov[ROWS][DIMH];

    const int t   = threadIdx.x;
    const int bid = blockIdx.x;
    const int b   = bid / (NB / ROWS);
    const int i0  = (bid % (NB / ROWS)) * ROWS;

    const float* hb = hidden + (size_t)b * NB * DIMH;

    // ---- stage h_i rows and ha table ----
    for (int idx = t; idx < ROWS * DIMH; idx += TPB) {
        int r = idx >> 7, d = idx & 127;
        hi[r][d] = hb[(i0 + r) * DIMH + d];
    }
    for (int idx = t; idx < ROWS * 4 * DIMH; idx += TPB) {
        int r = idx >> 9, k = (idx >> 7) & 3, d = idx & 127;
        float av = (k == 0) ? a0[d] : (k == 1) ? a1[d] : (k == 2) ? a2[d] : a3[d];
        ha[r][k][d] = hb[(i0 + r) * DIMH + d] * av;
    }
    __syncthreads();

    // ---- phase S: thread t owns column j=t for all 4 rows ----
    if (t < NB) {
        const int m = mask[b * NB + t];
        int kk[ROWS];
        #pragma unroll
        for (int r = 0; r < ROWS; r++)
            kk[r] = adj[((size_t)(b * NB + i0 + r)) * NB + t];
        int ksel[ROWS];
        #pragma unroll
        for (int r = 0; r < ROWS; r++) ksel[r] = (kk[r] > 0) ? (kk[r] - 1) : 0;

        float acc[ROWS] = {0.f, 0.f, 0.f, 0.f};
        const float* hj = hb + t * DIMH;
        #pragma unroll 4
        for (int d = 0; d < DIMH; d += 4) {
            float4 hv = *(const float4*)(hj + d);
            #pragma unroll
            for (int r = 0; r < ROWS; r++) {
                const float4 av4 = *(const float4*)&ha[r][ksel[r]][d];
                acc[r] = fmaf(hv.x, av4.x, acc[r]);
                acc[r] = fmaf(hv.y, av4.y, acc[r]);
                acc[r] = fmaf(hv.z, av4.z, acc[r]);
                acc[r] = fmaf(hv.w, av4.w, acc[r]);
            }
        }
        #pragma unroll
        for (int r = 0; r < ROWS; r++) {
            float x;
            if (m == 0)           x = -INFINITY;           // mask fill
            else if (kk[r] == 0)  x = 0.0f;                // no edge: sel=0
            else {
                float e = acc[r];
                e = (e >= 0.0f) ? e : 0.2f * e;            // leaky relu 0.2
                x = e * 0.1f;                              // * (alpha-1)
            }
            xs[r][t] = x;
        }
    } else {
        #pragma unroll
        for (int r = 0; r < ROWS; r++) xs[r][t] = -INFINITY;  // pad
    }
    __syncthreads();

    // ---- entmax bisection: wave r owns row i0+r (wave-local shuffle reduces) ----
    const int lane = t & 63;
    const int r    = t >> 6;
    float x0 = xs[r][lane];
    float x1 = xs[r][lane + 64];
    float x2 = xs[r][lane + 128];
    float x3 = xs[r][lane + 192];

    float mx  = wmax(fmaxf(fmaxf(x0, x1), fmaxf(x2, x3)));
    float tau = mx - 1.0f;
    float s0  = pow10_(fmaxf(x0 - tau, 0.f)) + pow10_(fmaxf(x1 - tau, 0.f))
              + pow10_(fmaxf(x2 - tau, 0.f)) + pow10_(fmaxf(x3 - tau, 0.f));
    float f_lo = wsum(s0) - 1.0f;                  // captured once (matches ref closure)
    float dm   = (mx - 0.58870401f) - tau;         // tau_hi - tau_lo; (1/200)^0.1

    for (int itn = 0; itn < NITER; ++itn) {
        dm *= 0.5f;
        float tm = tau + dm;
        float s = pow10_(fmaxf(x0 - tm, 0.f)) + pow10_(fmaxf(x1 - tm, 0.f))
                + pow10_(fmaxf(x2 - tm, 0.f)) + pow10_(fmaxf(x3 - tm, 0.f));
        float fm = wsum(s) - 1.0f;
        if (fm * f_lo >= 0.0f) tau = tm;
    }
    float p0 = pow10_(fmaxf(x0 - tau, 0.f));
    float p1 = pow10_(fmaxf(x1 - tau, 0.f));
    float p2 = pow10_(fmaxf(x2 - tau, 0.f));
    float p3 = pow10_(fmaxf(x3 - tau, 0.f));
    float sinv = 1.0f / wsum(p0 + p1 + p2 + p3);   // ensure_sum_one
    xs[r][lane]       = p0 * sinv;
    xs[r][lane + 64]  = p1 * sinv;
    xs[r][lane + 128] = p2 * sinv;
    xs[r][lane + 192] = p3 * sinv;
    // wave-local LDS write->read below: row owned by this wave, no barrier needed

    // ---- PV: out_row[d] = sum_j p[j]*h[b,j,d]; lane covers dims 2*lane, 2*lane+1 ----
    const int d0 = 2 * lane;
    float o0 = 0.f, o1 = 0.f;
    #pragma unroll 4
    for (int j = 0; j < NB; ++j) {
        float pj = xs[r][j];                       // broadcast read
        float2 hv = *(const float2*)(hb + j * DIMH + d0);
        o0 = fmaf(pj, hv.x, o0);
        o1 = fmaf(pj, hv.y, o1);
    }
    *(float2*)&ov[r][d0] = make_float2(o0, o1);

    // ---- gate: sigmoid([h_i, o] @ W + b), then mix ----
    float2 bv = *(const float2*)(bias + d0);
    float g0 = bv.x, g1 = bv.y;
    #pragma unroll 4
    for (int e = 0; e < DIMH; ++e) {
        float c = hi[r][e];                        // broadcast
        float2 wv = *(const float2*)(W + e * DIMH + d0);
        g0 = fmaf(c, wv.x, g0);
        g1 = fmaf(c, wv.y, g1);
    }
    #pragma unroll 4
    for (int e = 0; e < DIMH; ++e) {
        float c = ov[r][e];                        // broadcast
        float2 wv = *(const float2*)(W + (DIMH + e) * DIMH + d0);
        g0 = fmaf(c, wv.x, g0);
        g1 = fmaf(c, wv.y, g1);
    }
    float sg0 = 1.0f / (1.0f + __expf(-g0));
    float sg1 = 1.0f / (1.0f + __expf(-g1));

    float h0 = hi[r][d0], h1 = hi[r][d0 + 1];
    const size_t gi = (size_t)(b * NB + i0 + r) * DIMH;
    *(float2*)(out + gi + d0) =
        make_float2(sg0 * o0 + (1.0f - sg0) * h0,
                    sg1 * o1 + (1.0f - sg1) * h1);
}

extern "C" void kernel_launch(void* const* d_in, const int* in_sizes, int n_in,
                              void* d_out, int out_size, void* d_ws, size_t ws_size,
                              hipStream_t stream)
{
    const float* hidden = (const float*)d_in[0];
    const int*   adj    = (const int*)d_in[1];
    const int*   mask   = (const int*)d_in[2];
    const float* a0     = (const float*)d_in[3];
    const float* a1     = (const float*)d_in[4];
    const float* a2     = (const float*)d_in[5];
    const float* a3     = (const float*)d_in[6];
    const float* W      = (const float*)d_in[7];
    const float* bias   = (const float*)d_in[8];
    float* out = (float*)d_out;

    const int B = in_sizes[0] / (NB * DIMH);   // 256
    dim3 grid(B * (NB / ROWS));
    la_fused<<<grid, TPB, 0, stream>>>(hidden, adj, mask, a0, a1, a2, a3, W, bias, out);
}

// Round 3
// 814.339 us; speedup vs baseline: 2.0303x; 1.0166x over previous
//
#include <hip/hip_runtime.h>
#include <math.h>

#define NB    200
#define DIMH  128
#define ROWS  4
#define TPB   256
#define NITER 22   // 50 in ref; tau err <= 0.411*2^-22 ~ 1e-7 -> p err ~1e-6, well under threshold

__device__ __forceinline__ float pow10_(float x){
    float x2 = x*x; float x4 = x2*x2; float x8 = x4*x4; return x8*x2;
}

// Wave64 sum-reduce via DPP (row_shr 1/2/4/8 + row_bcast 15/31), result uniform (readlane 63).
// ~30 cy dependent latency vs ~200 cy for 6x ds_swizzle shuffles.
__device__ __forceinline__ float wsum_dpp(float v){
#define DPP_ADD(ctrl, rmask)                                                     \
    {                                                                            \
        int t_ = __builtin_amdgcn_update_dpp(0, __builtin_bit_cast(int, v),      \
                                             ctrl, rmask, 0xf, false);           \
        v += __builtin_bit_cast(float, t_);                                      \
    }
    DPP_ADD(0x111, 0xf)   // row_shr:1
    DPP_ADD(0x112, 0xf)   // row_shr:2
    DPP_ADD(0x114, 0xf)   // row_shr:4
    DPP_ADD(0x118, 0xf)   // row_shr:8  -> lane15 of each 16-row holds row sum
    DPP_ADD(0x142, 0xa)   // row_bcast:15 -> rows 1,3 accumulate rows 0,2
    DPP_ADD(0x143, 0xc)   // row_bcast:31 -> rows 2,3 accumulate pair sum; lane63 = total
#undef DPP_ADD
    return __builtin_bit_cast(float,
        __builtin_amdgcn_readlane(__builtin_bit_cast(int, v), 63));
}

__device__ __forceinline__ float wmax_dpp(float v){
#define DPP_MAX(ctrl, rmask)                                                     \
    {                                                                            \
        int t_ = __builtin_amdgcn_update_dpp(__builtin_bit_cast(int, v),         \
                                             __builtin_bit_cast(int, v),         \
                                             ctrl, rmask, 0xf, false);           \
        v = fmaxf(v, __builtin_bit_cast(float, t_));                             \
    }
    DPP_MAX(0x111, 0xf)
    DPP_MAX(0x112, 0xf)
    DPP_MAX(0x114, 0xf)
    DPP_MAX(0x118, 0xf)
    DPP_MAX(0x142, 0xa)
    DPP_MAX(0x143, 0xc)
#undef DPP_MAX
    return __builtin_bit_cast(float,
        __builtin_amdgcn_readlane(__builtin_bit_cast(int, v), 63));
}

__global__ __launch_bounds__(TPB, 4) void la_fused(
    const float* __restrict__ hidden,
    const int*   __restrict__ adj,
    const int*   __restrict__ mask,
    const float* __restrict__ a0, const float* __restrict__ a1,
    const float* __restrict__ a2, const float* __restrict__ a3,
    const float* __restrict__ W,  const float* __restrict__ bias,
    float* __restrict__ out)
{
    __shared__ float ha[ROWS][4][132];   // h_i[d]*a_k[d], padded stride
    __shared__ float hi[ROWS][DIMH];
    __shared__ float xs[ROWS][256];      // Xs, later normalized p
    __shared__ float ov[ROWS][DIMH];

    const int t   = threadIdx.x;
    const int bid = blockIdx.x;
    const int b   = bid / (NB / ROWS);
    const int i0  = (bid % (NB / ROWS)) * ROWS;

    const float* hb = hidden + (size_t)b * NB * DIMH;

    // ---- stage h_i rows and ha table ----
    for (int idx = t; idx < ROWS * DIMH; idx += TPB) {
        int r = idx >> 7, d = idx & 127;
        hi[r][d] = hb[(i0 + r) * DIMH + d];
    }
    for (int idx = t; idx < ROWS * 4 * DIMH; idx += TPB) {
        int r = idx >> 9, k = (idx >> 7) & 3, d = idx & 127;
        float av = (k == 0) ? a0[d] : (k == 1) ? a1[d] : (k == 2) ? a2[d] : a3[d];
        ha[r][k][d] = hb[(i0 + r) * DIMH + d] * av;
    }
    __syncthreads();

    // ---- phase S: thread t owns column j=t for all 4 rows ----
    if (t < NB) {
        const int m = mask[b * NB + t];
        int kk[ROWS];
        #pragma unroll
        for (int r = 0; r < ROWS; r++)
            kk[r] = adj[((size_t)(b * NB + i0 + r)) * NB + t];
        int ksel[ROWS];
        #pragma unroll
        for (int r = 0; r < ROWS; r++) ksel[r] = (kk[r] > 0) ? (kk[r] - 1) : 0;

        float acc[ROWS] = {0.f, 0.f, 0.f, 0.f};
        const float* hj = hb + t * DIMH;
        #pragma unroll 4
        for (int d = 0; d < DIMH; d += 4) {
            float4 hv = *(const float4*)(hj + d);
            #pragma unroll
            for (int r = 0; r < ROWS; r++) {
                const float4 av4 = *(const float4*)&ha[r][ksel[r]][d];
                acc[r] = fmaf(hv.x, av4.x, acc[r]);
                acc[r] = fmaf(hv.y, av4.y, acc[r]);
                acc[r] = fmaf(hv.z, av4.z, acc[r]);
                acc[r] = fmaf(hv.w, av4.w, acc[r]);
            }
        }
        #pragma unroll
        for (int r = 0; r < ROWS; r++) {
            float x;
            if (m == 0)           x = -INFINITY;           // mask fill
            else if (kk[r] == 0)  x = 0.0f;                // no edge: sel=0
            else {
                float e = acc[r];
                e = (e >= 0.0f) ? e : 0.2f * e;            // leaky relu 0.2
                x = e * 0.1f;                              // * (alpha-1)
            }
            xs[r][t] = x;
        }
    } else {
        #pragma unroll
        for (int r = 0; r < ROWS; r++) xs[r][t] = -INFINITY;  // pad
    }
    __syncthreads();

    // ---- entmax bisection: wave r owns row i0+r (DPP reduces, scalar tau updates) ----
    const int lane = t & 63;
    const int r    = t >> 6;
    float x0 = xs[r][lane];
    float x1 = xs[r][lane + 64];
    float x2 = xs[r][lane + 128];
    float x3 = xs[r][lane + 192];

    float mx  = wmax_dpp(fmaxf(fmaxf(x0, x1), fmaxf(x2, x3)));
    float tau = mx - 1.0f;
    float s0  = pow10_(fmaxf(x0 - tau, 0.f)) + pow10_(fmaxf(x1 - tau, 0.f))
              + pow10_(fmaxf(x2 - tau, 0.f)) + pow10_(fmaxf(x3 - tau, 0.f));
    float f_lo = wsum_dpp(s0) - 1.0f;              // captured once (matches ref closure)
    float dm   = (mx - 0.58870401f) - tau;         // tau_hi - tau_lo; (1/200)^0.1

    for (int itn = 0; itn < NITER; ++itn) {
        dm *= 0.5f;
        float tm = tau + dm;
        float s = pow10_(fmaxf(x0 - tm, 0.f)) + pow10_(fmaxf(x1 - tm, 0.f))
                + pow10_(fmaxf(x2 - tm, 0.f)) + pow10_(fmaxf(x3 - tm, 0.f));
        float fm = wsum_dpp(s) - 1.0f;
        if (fm * f_lo >= 0.0f) tau = tm;
    }
    float p0 = pow10_(fmaxf(x0 - tau, 0.f));
    float p1 = pow10_(fmaxf(x1 - tau, 0.f));
    float p2 = pow10_(fmaxf(x2 - tau, 0.f));
    float p3 = pow10_(fmaxf(x3 - tau, 0.f));
    float sinv = 1.0f / wsum_dpp(p0 + p1 + p2 + p3);   // ensure_sum_one
    xs[r][lane]       = p0 * sinv;
    xs[r][lane + 64]  = p1 * sinv;
    xs[r][lane + 128] = p2 * sinv;
    xs[r][lane + 192] = p3 * sinv;
    // wave-local LDS write->read below: row owned by this wave, no barrier needed

    // ---- PV: out_row[d] = sum_j p[j]*h[b,j,d]; lane covers dims 2*lane, 2*lane+1 ----
    const int d0 = 2 * lane;
    float o0 = 0.f, o1 = 0.f;
    #pragma unroll 4
    for (int j = 0; j < NB; ++j) {
        float pj = xs[r][j];                       // broadcast read
        float2 hv = *(const float2*)(hb + j * DIMH + d0);
        o0 = fmaf(pj, hv.x, o0);
        o1 = fmaf(pj, hv.y, o1);
    }
    *(float2*)&ov[r][d0] = make_float2(o0, o1);

    // ---- gate: sigmoid([h_i, o] @ W + b), then mix ----
    float2 bv = *(const float2*)(bias + d0);
    float g0 = bv.x, g1 = bv.y;
    #pragma unroll 4
    for (int e = 0; e < DIMH; ++e) {
        float c = hi[r][e];                        // broadcast
        float2 wv = *(const float2*)(W + e * DIMH + d0);
        g0 = fmaf(c, wv.x, g0);
        g1 = fmaf(c, wv.y, g1);
    }
    #pragma unroll 4
    for (int e = 0; e < DIMH; ++e) {
        float c = ov[r][e];                        // broadcast
        float2 wv = *(const float2*)(W + (DIMH + e) * DIMH + d0);
        g0 = fmaf(c, wv.x, g0);
        g1 = fmaf(c, wv.y, g1);
    }
    float sg0 = 1.0f / (1.0f + __expf(-g0));
    float sg1 = 1.0f / (1.0f + __expf(-g1));

    float h0 = hi[r][d0], h1 = hi[r][d0 + 1];
    const size_t gi = (size_t)(b * NB + i0 + r) * DIMH;
    *(float2*)(out + gi + d0) =
        make_float2(sg0 * o0 + (1.0f - sg0) * h0,
                    sg1 * o1 + (1.0f - sg1) * h1);
}

extern "C" void kernel_launch(void* const* d_in, const int* in_sizes, int n_in,
                              void* d_out, int out_size, void* d_ws, size_t ws_size,
                              hipStream_t stream)
{
    const float* hidden = (const float*)d_in[0];
    const int*   adj    = (const int*)d_in[1];
    const int*   mask   = (const int*)d_in[2];
    const float* a0     = (const float*)d_in[3];
    const float* a1     = (const float*)d_in[4];
    const float* a2     = (const float*)d_in[5];
    const float* a3     = (const float*)d_in[6];
    const float* W      = (const float*)d_in[7];
    const float* bias   = (const float*)d_in[8];
    float* out = (float*)d_out;

    const int B = in_sizes[0] / (NB * DIMH);   // 256
    dim3 grid(B * (NB / ROWS));
    la_fused<<<grid, TPB, 0, stream>>>(hidden, adj, mask, a0, a1, a2, a3, W, bias, out);
}